// Round 1
// baseline (889.415 us; speedup 1.0000x reference)
//
#include <hip/hip_runtime.h>
#include <math.h>

// SASRec loss on MI355X — round 0: correctness-first full-f32 implementation.
// B=256 L=200 D=128 H=4 NB=2, ITEMS=50000.
#define B_ 256
#define L_ 200
#define D_ 128
#define H_ 4
#define HD_ 32
#define NB_ 2
#define NROWS (B_ * L_)        // 51200
#define NITEMS 50001
#define EPS_ 1e-8f
#define C_ 0.001f
#define REG_ 0.0001f

// ---------------------------------------------------------------- embed
// X[b,l,:] = item_emb[log_seqs[b,l]] + pos_emb[(l+1)*(log!=0)]
__global__ __launch_bounds__(256) void k_embed(const int* __restrict__ logs,
                                               const float* __restrict__ item_emb,
                                               const float* __restrict__ pos_emb,
                                               float* __restrict__ X) {
  int gid = blockIdx.x * 256 + threadIdx.x;   // one float4 per thread
  if (gid >= NROWS * 32) return;
  int row = gid >> 5;
  int c4  = (gid & 31) << 2;
  int it  = logs[row];
  int l   = row % L_;
  int pos = (it != 0) ? (l + 1) : 0;
  float4 e = *(const float4*)(item_emb + (size_t)it * D_ + c4);
  float4 p = *(const float4*)(pos_emb + (size_t)pos * D_ + c4);
  float4 o; o.x = e.x + p.x; o.y = e.y + p.y; o.z = e.z + p.z; o.w = e.w + p.w;
  *(float4*)(X + (size_t)row * D_ + c4) = o;
}

// ---------------------------------------------------------------- layernorm
// one wave per row of 128; lane handles 2 cols. exact two-pass (mean, then var).
__global__ __launch_bounds__(256) void k_ln(const float* __restrict__ in,
                                            const float* __restrict__ g,
                                            const float* __restrict__ bb,
                                            float* __restrict__ out) {
  int wid = threadIdx.x >> 6, lane = threadIdx.x & 63;
  int row = blockIdx.x * 4 + wid;
  float2 x = *(const float2*)(in + (size_t)row * D_ + lane * 2);
  float s = x.x + x.y;
#pragma unroll
  for (int o = 1; o < 64; o <<= 1) s += __shfl_xor(s, o, 64);
  float m = s * (1.f / D_);
  float d0 = x.x - m, d1 = x.y - m;
  float ss = d0 * d0 + d1 * d1;
#pragma unroll
  for (int o = 1; o < 64; o <<= 1) ss += __shfl_xor(ss, o, 64);
  float rs = 1.f / sqrtf(ss * (1.f / D_) + EPS_);
  float2 gv = *(const float2*)(g + lane * 2);
  float2 bv = *(const float2*)(bb + lane * 2);
  float2 o2; o2.x = d0 * rs * gv.x + bv.x; o2.y = d1 * rs * gv.y + bv.y;
  *(float2*)(out + (size_t)row * D_ + lane * 2) = o2;
}

// ---------------------------------------------------------------- f32 GEMM
// C[M,N] = epi(A[M,K=128] * W[N,128]^T + bias, Res). 64x64 tile, 4x4/thread.
// epi: 0 = bias, 1 = bias + residual (Res stride 128), 2 = bias + relu
__global__ __launch_bounds__(256) void k_gemm(const float* __restrict__ A, int lda,
                                              const float* __restrict__ W,
                                              const float* __restrict__ bias,
                                              const float* __restrict__ Res,
                                              float* __restrict__ Cmat, int ldc,
                                              int col0, int epi) {
  __shared__ float As[16][64];   // [k][m]
  __shared__ float Bs[16][64];   // [k][n]
  const int tid = threadIdx.x;
  const int bm = blockIdx.x * 64, bn = blockIdx.y * 64;
  const int lr = tid >> 2;            // 0..63 tile row
  const int lc = (tid & 3) << 2;      // k sub-offset 0/4/8/12
  const int m0 = (tid >> 4) << 2;     // 0..60
  const int n0 = (tid & 15) << 2;     // 0..60
  float acc[4][4] = {{0.f}};
  const float* Ap = A + (size_t)(bm + lr) * lda + lc;
  const float* Wp = W + (size_t)(bn + lr) * D_ + lc;
  for (int kt = 0; kt < 128; kt += 16) {
    float4 a4 = *(const float4*)(Ap + kt);
    float4 w4 = *(const float4*)(Wp + kt);
    __syncthreads();
    As[lc + 0][lr] = a4.x; As[lc + 1][lr] = a4.y; As[lc + 2][lr] = a4.z; As[lc + 3][lr] = a4.w;
    Bs[lc + 0][lr] = w4.x; Bs[lc + 1][lr] = w4.y; Bs[lc + 2][lr] = w4.z; Bs[lc + 3][lr] = w4.w;
    __syncthreads();
#pragma unroll
    for (int k = 0; k < 16; k++) {
      float4 av = *(const float4*)&As[k][m0];
      float4 bv = *(const float4*)&Bs[k][n0];
      acc[0][0] += av.x * bv.x; acc[0][1] += av.x * bv.y; acc[0][2] += av.x * bv.z; acc[0][3] += av.x * bv.w;
      acc[1][0] += av.y * bv.x; acc[1][1] += av.y * bv.y; acc[1][2] += av.y * bv.z; acc[1][3] += av.y * bv.w;
      acc[2][0] += av.z * bv.x; acc[2][1] += av.z * bv.y; acc[2][2] += av.z * bv.z; acc[2][3] += av.z * bv.w;
      acc[3][0] += av.w * bv.x; acc[3][1] += av.w * bv.y; acc[3][2] += av.w * bv.z; acc[3][3] += av.w * bv.w;
    }
  }
  float4 b4 = *(const float4*)(bias + bn + n0);
#pragma unroll
  for (int i = 0; i < 4; i++) {
    int row = bm + m0 + i;
    float4 v;
    v.x = acc[i][0] + b4.x; v.y = acc[i][1] + b4.y;
    v.z = acc[i][2] + b4.z; v.w = acc[i][3] + b4.w;
    if (epi == 2) {
      v.x = fmaxf(v.x, 0.f); v.y = fmaxf(v.y, 0.f);
      v.z = fmaxf(v.z, 0.f); v.w = fmaxf(v.w, 0.f);
    } else if (epi == 1) {
      float4 r4 = *(const float4*)(Res + (size_t)row * D_ + bn + n0);
      v.x += r4.x; v.y += r4.y; v.z += r4.z; v.w += r4.w;
    }
    *(float4*)(Cmat + (size_t)row * ldc + col0 + bn + n0) = v;
  }
}

// ---------------------------------------------------------------- attention
// one block per (b,h); K/V staged in LDS; one thread per query row, online softmax.
// Output written into the (dead) q slice of the qkv buffer — race-free: each
// thread reads only its own q row (before writing it), h-slices are disjoint.
__global__ __launch_bounds__(256) void k_attn(const float* __restrict__ qkv,
                                              float* __restrict__ Oq) {
  __shared__ float ks[L_][HD_];
  __shared__ float vs[L_][HD_];
  int b = blockIdx.x >> 2;    // H_ == 4
  int h = blockIdx.x & 3;
  int tid = threadIdx.x;
  for (int idx = tid; idx < L_ * HD_; idx += 256) {
    int j = idx >> 5, d = idx & 31;
    size_t base = ((size_t)(b * L_ + j)) * 384 + 128 + h * HD_ + d;
    ks[j][d] = qkv[base];
    vs[j][d] = qkv[base + 128];
  }
  __syncthreads();
  int t = tid;
  if (t >= L_) return;
  float q[HD_];
  const float* qp = qkv + ((size_t)(b * L_ + t)) * 384 + h * HD_;
#pragma unroll
  for (int d4 = 0; d4 < HD_; d4 += 4) {
    float4 v = *(const float4*)(qp + d4);
    q[d4] = v.x; q[d4 + 1] = v.y; q[d4 + 2] = v.z; q[d4 + 3] = v.w;
  }
  float o[HD_];
#pragma unroll
  for (int d = 0; d < HD_; d++) o[d] = 0.f;
  float mrun = -INFINITY, lrun = 0.f;
  const float scale = 0.17677669529663687f;   // 1/sqrt(32)
  for (int j = 0; j <= t; j++) {
    float s = 0.f;
#pragma unroll
    for (int d = 0; d < HD_; d++) s += q[d] * ks[j][d];
    s *= scale;
    float mn = fmaxf(mrun, s);
    float corr = __expf(mrun - mn);   // exp(-inf)=0 handles first iter
    float p = __expf(s - mn);
    lrun = lrun * corr + p;
#pragma unroll
    for (int d = 0; d < HD_; d++) o[d] = o[d] * corr + p * vs[j][d];
    mrun = mn;
  }
  float inv = 1.f / lrun;
  float* op = Oq + ((size_t)(b * L_ + t)) * 384 + h * HD_;
#pragma unroll
  for (int d4 = 0; d4 < HD_; d4 += 4) {
    float4 v;
    v.x = o[d4] * inv; v.y = o[d4 + 1] * inv;
    v.z = o[d4 + 2] * inv; v.w = o[d4 + 3] * inv;
    *(float4*)(op + d4) = v;
  }
}

// ---------------------------------------------------------------- loss pieces
__global__ void k_zero(float* __restrict__ w_raw, float* __restrict__ reg_sq) {
  int t = threadIdx.x;
  if (t < 128) w_raw[t] = 0.f;
  if (t == 128) reg_sq[0] = 0.f;
}

// one pass over item_emb: w_raw[e] = sum_i E[i,e]*dot(E[i],p); reg_sq = sum E^2
__global__ __launch_bounds__(256) void k_wreg(const float* __restrict__ item_emb,
                                              const float* __restrict__ pred_w,
                                              float* __restrict__ w_raw,
                                              float* __restrict__ reg_sq) {
  int gw = (blockIdx.x * 256 + threadIdx.x) >> 6;   // global wave 0..1023
  int lane = threadIdx.x & 63;
  float2 p2 = *(const float2*)(pred_w + lane * 2);
  float ax = 0.f, ay = 0.f, ssq = 0.f;
  for (int r = gw; r < NITEMS; r += 1024) {
    float2 e = *(const float2*)(item_emb + (size_t)r * D_ + lane * 2);
    float dp = e.x * p2.x + e.y * p2.y;
#pragma unroll
    for (int o = 1; o < 64; o <<= 1) dp += __shfl_xor(dp, o, 64);
    ax += e.x * dp; ay += e.y * dp;
    ssq += e.x * e.x + e.y * e.y;
  }
  atomicAdd(&w_raw[lane * 2 + 0], ax);
  atomicAdd(&w_raw[lane * 2 + 1], ay);
#pragma unroll
  for (int o = 1; o < 64; o <<= 1) ssq += __shfl_xor(ssq, o, 64);
  if (lane == 0) atomicAdd(reg_sq, ssq);
}

// wt[e] = C * (sum p) * w_raw[e];  out = REG*||E||_F (base value, overwritten-poison safe)
__global__ void k_scale(const float* __restrict__ pred_w,
                        const float* __restrict__ w_raw,
                        const float* __restrict__ reg_sq,
                        float* __restrict__ wt, float* __restrict__ out) {
  int t = threadIdx.x;   // 128 threads
  __shared__ float sp[128];
  sp[t] = pred_w[t];
  __syncthreads();
  float S = 0.f;
  for (int i = 0; i < 128; i++) S += sp[i];
  wt[t] = C_ * S * w_raw[t];
  if (t == 0) out[0] = REG_ * sqrtf(reg_sq[0]);
}

// per-batch: left = sum_s rowsum(F_s)*dot(F_s,wt); right = sum_s (1-C)R^2-2R
__global__ __launch_bounds__(256) void k_final(const float* __restrict__ F,
                                               const int* __restrict__ pos_seqs,
                                               const float* __restrict__ item_emb,
                                               const float* __restrict__ pred_w,
                                               const float* __restrict__ wt,
                                               float* __restrict__ out) {
  int b = blockIdx.x;
  int wid = threadIdx.x >> 6, lane = threadIdx.x & 63;
  float2 wt2 = *(const float2*)(wt + lane * 2);
  float2 p2  = *(const float2*)(pred_w + lane * 2);
  float acc = 0.f;
  for (int s = wid; s < L_; s += 4) {
    float2 f = *(const float2*)(F + ((size_t)(b * L_ + s)) * D_ + lane * 2);
    int pi = pos_seqs[b * L_ + s];
    float2 pe = *(const float2*)(item_emb + (size_t)pi * D_ + lane * 2);
    float rsum = f.x + f.y;
    float dw = f.x * wt2.x + f.y * wt2.y;
    float rr = p2.x * f.x * pe.x + p2.y * f.y * pe.y;
#pragma unroll
    for (int o = 1; o < 64; o <<= 1) {
      rsum += __shfl_xor(rsum, o, 64);
      dw   += __shfl_xor(dw, o, 64);
      rr   += __shfl_xor(rr, o, 64);
    }
    acc += rsum * dw + (1.f - C_) * rr * rr - 2.f * rr;
  }
  if (lane == 0) atomicAdd(out, acc * (1.f / B_));
}

// ---------------------------------------------------------------- launch
extern "C" void kernel_launch(void* const* d_in, const int* in_sizes, int n_in,
                              void* d_out, int out_size, void* d_ws, size_t ws_size,
                              hipStream_t stream) {
  const int*   log_seqs = (const int*)d_in[1];
  const int*   pos_seqs = (const int*)d_in[2];
  const float* item_emb = (const float*)d_in[3];
  const float* pos_emb  = (const float*)d_in[4];
  const float* pred_w   = (const float*)d_in[5];
  const float* ln1_g = (const float*)d_in[6];
  const float* ln1_b = (const float*)d_in[7];
  const float* in_w  = (const float*)d_in[8];
  const float* in_b  = (const float*)d_in[9];
  const float* out_w = (const float*)d_in[10];
  const float* out_b = (const float*)d_in[11];
  const float* ln2_g = (const float*)d_in[12];
  const float* ln2_b = (const float*)d_in[13];
  const float* c1_w  = (const float*)d_in[14];
  const float* c1_b  = (const float*)d_in[15];
  const float* c2_w  = (const float*)d_in[16];
  const float* c2_b  = (const float*)d_in[17];
  float* out = (float*)d_out;

  char* ws = (char*)d_ws;
  const size_t UNIT = (size_t)NROWS * D_ * sizeof(float);   // 26.2 MB
  float* X     = (float*)ws; ws += UNIT;        // seqs / F
  float* QB    = (float*)ws; ws += UNIT;        // LN outputs / residual
  float* QKV   = (float*)ws; ws += 3 * UNIT;    // qkv (384-wide); also attn-out & FFN hidden
  float* w_raw = (float*)ws; ws += 512;
  float* wt    = (float*)ws; ws += 512;
  float* reg_sq= (float*)ws; ws += 512;
  if (ws_size < 5 * UNIT + 4096) return;  // workspace too small -> fail loudly

  k_zero<<<1, 256, 0, stream>>>(w_raw, reg_sq);
  k_embed<<<(NROWS * 32) / 256, 256, 0, stream>>>(log_seqs, item_emb, pos_emb, X);

  for (int i = 0; i < NB_; i++) {
    const float* iw = in_w + (size_t)i * 384 * 128;
    const float* ib = in_b + (size_t)i * 384;
    // Q = LN1(X)
    k_ln<<<NROWS / 4, 256, 0, stream>>>(X, ln1_g + i * 128, ln1_b + i * 128, QB);
    // q = QB @ Wq^T + bq          -> QKV[:, 0:128]
    k_gemm<<<dim3(NROWS / 64, 2), 256, 0, stream>>>(QB, 128, iw, ib, nullptr, QKV, 384, 0, 0);
    // k,v = X @ [Wk;Wv]^T + b     -> QKV[:, 128:384]
    k_gemm<<<dim3(NROWS / 64, 4), 256, 0, stream>>>(X, 128, iw + 128 * 128, ib + 128,
                                                    nullptr, QKV, 384, 128, 0);
    // attention: softmax(qk^T)v   -> QKV[:, 0:128] (q slice, dead)
    k_attn<<<B_ * H_, 256, 0, stream>>>(QKV, QKV);
    // seqs = QB + attn @ Wo^T + bo -> X
    k_gemm<<<dim3(NROWS / 64, 2), 256, 0, stream>>>(QKV, 384, out_w + (size_t)i * 128 * 128,
                                                    out_b + i * 128, QB, X, 128, 0, 1);
    // Z = LN2 -> QB
    k_ln<<<NROWS / 4, 256, 0, stream>>>(X, ln2_g + i * 128, ln2_b + i * 128, QB);
    // H1 = relu(Z @ c1^T + b1) -> QKV (128-wide)
    k_gemm<<<dim3(NROWS / 64, 2), 256, 0, stream>>>(QB, 128, c1_w + (size_t)i * 128 * 128,
                                                    c1_b + i * 128, nullptr, QKV, 128, 0, 2);
    // X = Z + H1 @ c2^T + b2
    k_gemm<<<dim3(NROWS / 64, 2), 256, 0, stream>>>(QKV, 128, c2_w + (size_t)i * 128 * 128,
                                                    c2_b + i * 128, QB, X, 128, 0, 1);
  }

  k_wreg<<<256, 256, 0, stream>>>(item_emb, pred_w, w_raw, reg_sq);
  k_scale<<<1, 128, 0, stream>>>(pred_w, w_raw, reg_sq, wt, out);
  k_final<<<B_, 256, 0, stream>>>(X, pos_seqs, item_emb, pred_w, wt, out);
}

// Round 3
// 830.071 us; speedup vs baseline: 1.0715x; 1.0715x over previous
//
#include <hip/hip_runtime.h>
#include <math.h>

// SASRec loss on MI355X — round 2 (resubmit): GEMMs on split-bf16 MFMA (hi/lo
// decomposition, 3 products, ~1e-5 relative error). Attention unchanged.
// B=256 L=200 D=128 H=4 NB=2, ITEMS=50000.
#define B_ 256
#define L_ 200
#define D_ 128
#define H_ 4
#define HD_ 32
#define NB_ 2
#define NROWS (B_ * L_)        // 51200
#define NITEMS 50001
#define EPS_ 1e-8f
#define C_ 0.001f
#define REG_ 0.0001f

typedef __bf16 bf16x8 __attribute__((ext_vector_type(8)));
typedef short  short8 __attribute__((ext_vector_type(8)));
typedef float  f32x4  __attribute__((ext_vector_type(4)));

static __device__ __forceinline__ unsigned short f2bf(float f) {
  unsigned u = __builtin_bit_cast(unsigned, f);
  unsigned r = (u + 0x7FFFu + ((u >> 16) & 1u)) >> 16;   // RTN-even
  return (unsigned short)r;
}
static __device__ __forceinline__ float bf2f(unsigned short s) {
  return __builtin_bit_cast(float, (unsigned)s << 16);
}

// ---------------------------------------------------------------- embed
__global__ __launch_bounds__(256) void k_embed(const int* __restrict__ logs,
                                               const float* __restrict__ item_emb,
                                               const float* __restrict__ pos_emb,
                                               float* __restrict__ X) {
  int gid = blockIdx.x * 256 + threadIdx.x;   // one float4 per thread
  if (gid >= NROWS * 32) return;
  int row = gid >> 5;
  int c4  = (gid & 31) << 2;
  int it  = logs[row];
  int l   = row % L_;
  int pos = (it != 0) ? (l + 1) : 0;
  float4 e = *(const float4*)(item_emb + (size_t)it * D_ + c4);
  float4 p = *(const float4*)(pos_emb + (size_t)pos * D_ + c4);
  float4 o; o.x = e.x + p.x; o.y = e.y + p.y; o.z = e.z + p.z; o.w = e.w + p.w;
  *(float4*)(X + (size_t)row * D_ + c4) = o;
}

// ---------------------------------------------------------------- layernorm
__global__ __launch_bounds__(256) void k_ln(const float* __restrict__ in,
                                            const float* __restrict__ g,
                                            const float* __restrict__ bb,
                                            float* __restrict__ out) {
  int wid = threadIdx.x >> 6, lane = threadIdx.x & 63;
  int row = blockIdx.x * 4 + wid;
  float2 x = *(const float2*)(in + (size_t)row * D_ + lane * 2);
  float s = x.x + x.y;
#pragma unroll
  for (int o = 1; o < 64; o <<= 1) s += __shfl_xor(s, o, 64);
  float m = s * (1.f / D_);
  float d0 = x.x - m, d1 = x.y - m;
  float ss = d0 * d0 + d1 * d1;
#pragma unroll
  for (int o = 1; o < 64; o <<= 1) ss += __shfl_xor(ss, o, 64);
  float rs = 1.f / sqrtf(ss * (1.f / D_) + EPS_);
  float2 gv = *(const float2*)(g + lane * 2);
  float2 bv = *(const float2*)(bb + lane * 2);
  float2 o2; o2.x = d0 * rs * gv.x + bv.x; o2.y = d1 * rs * gv.y + bv.y;
  *(float2*)(out + (size_t)row * D_ + lane * 2) = o2;
}

// ---------------------------------------------------------------- MFMA GEMM
// C[M,128-chunk] = epi(A[M,K=128] @ W[N,128]^T + bias, Res)
// split-bf16: a = ah + al; a*b ~= ah*bh + ah*bl + al*bh  (err ~2^-17)
// grid: (M/64, n_chunks). Tile 64x128, 4 waves each 64x32.
// epi: 0 = bias, 1 = bias + residual (stride 128), 2 = bias + relu
__global__ __launch_bounds__(256) void k_gemm_mfma(const float* __restrict__ A, int lda,
                                                   const float* __restrict__ W,
                                                   const float* __restrict__ bias,
                                                   const float* __restrict__ Res,
                                                   float* __restrict__ Cmat, int ldc,
                                                   int col0, int epi) {
  W    += (size_t)blockIdx.y * 128 * 128;
  bias += blockIdx.y * 128;
  col0 += blockIdx.y * 128;
  __shared__ float As[64][132];          // +4 pad -> 2-way conflicts only
  const int tid  = threadIdx.x;
  const int bm   = blockIdx.x * 64;
  const int lane = tid & 63, wid = tid >> 6;
  const int n0   = wid * 32;
  const int fr   = lane & 15;            // fragment row/col
  const int fg   = lane >> 4;            // k-group (8 contiguous k)

  // W fragments -> registers (hi/lo), reused for the whole tile
  bf16x8 bh[2][4], bl[2][4];
#pragma unroll
  for (int f = 0; f < 2; f++)
#pragma unroll
    for (int ks = 0; ks < 4; ks++) {
      const float* wp = W + (size_t)(n0 + f * 16 + fr) * 128 + ks * 32 + fg * 8;
      float4 w0 = *(const float4*)wp;
      float4 w1 = *(const float4*)(wp + 4);
      float wf[8] = {w0.x, w0.y, w0.z, w0.w, w1.x, w1.y, w1.z, w1.w};
      short8 h, l2;
#pragma unroll
      for (int j = 0; j < 8; j++) {
        unsigned short hb = f2bf(wf[j]);
        h[j]  = (short)hb;
        l2[j] = (short)f2bf(wf[j] - bf2f(hb));
      }
      bh[f][ks] = __builtin_bit_cast(bf16x8, h);
      bl[f][ks] = __builtin_bit_cast(bf16x8, l2);
    }

  // stage A tile (64x128 f32) into padded LDS, coalesced
#pragma unroll
  for (int i = 0; i < 8; i++) {
    int flat = i * 1024 + tid * 4;
    int r = flat >> 7, c = flat & 127;
    float4 v = *(const float4*)(A + (size_t)(bm + r) * lda + c);
    *(float4*)&As[r][c] = v;
  }
  __syncthreads();

  f32x4 acc[4][2];
#pragma unroll
  for (int m = 0; m < 4; m++)
#pragma unroll
    for (int f = 0; f < 2; f++) acc[m][f] = (f32x4)0.f;

#pragma unroll
  for (int m = 0; m < 4; m++) {
#pragma unroll
    for (int ks = 0; ks < 4; ks++) {
      const float* ap = &As[m * 16 + fr][ks * 32 + fg * 8];
      float4 a0 = *(const float4*)ap;
      float4 a1 = *(const float4*)(ap + 4);
      float af[8] = {a0.x, a0.y, a0.z, a0.w, a1.x, a1.y, a1.z, a1.w};
      short8 h, l2;
#pragma unroll
      for (int j = 0; j < 8; j++) {
        unsigned short hb = f2bf(af[j]);
        h[j]  = (short)hb;
        l2[j] = (short)f2bf(af[j] - bf2f(hb));
      }
      bf16x8 ah = __builtin_bit_cast(bf16x8, h);
      bf16x8 al = __builtin_bit_cast(bf16x8, l2);
#pragma unroll
      for (int f = 0; f < 2; f++) {
        acc[m][f] = __builtin_amdgcn_mfma_f32_16x16x32_bf16(ah, bl[f][ks], acc[m][f], 0, 0, 0);
        acc[m][f] = __builtin_amdgcn_mfma_f32_16x16x32_bf16(al, bh[f][ks], acc[m][f], 0, 0, 0);
        acc[m][f] = __builtin_amdgcn_mfma_f32_16x16x32_bf16(ah, bh[f][ks], acc[m][f], 0, 0, 0);
      }
    }
  }

  // epilogue: C/D layout row=(lane>>4)*4+i, col=lane&15
#pragma unroll
  for (int f = 0; f < 2; f++) {
    int n = n0 + f * 16 + fr;
    float bv = bias[n];
#pragma unroll
    for (int m = 0; m < 4; m++) {
#pragma unroll
      for (int i = 0; i < 4; i++) {
        int row = bm + m * 16 + fg * 4 + i;
        float v = acc[m][f][i] + bv;
        if (epi == 2)      v = fmaxf(v, 0.f);
        else if (epi == 1) v += Res[(size_t)row * D_ + n];
        Cmat[(size_t)row * ldc + col0 + n] = v;
      }
    }
  }
}

// ---------------------------------------------------------------- attention
__global__ __launch_bounds__(256) void k_attn(const float* __restrict__ qkv,
                                              float* __restrict__ Oq) {
  __shared__ float ks[L_][HD_];
  __shared__ float vs[L_][HD_];
  int b = blockIdx.x >> 2;    // H_ == 4
  int h = blockIdx.x & 3;
  int tid = threadIdx.x;
  for (int idx = tid; idx < L_ * HD_; idx += 256) {
    int j = idx >> 5, d = idx & 31;
    size_t base = ((size_t)(b * L_ + j)) * 384 + 128 + h * HD_ + d;
    ks[j][d] = qkv[base];
    vs[j][d] = qkv[base + 128];
  }
  __syncthreads();
  int t = tid;
  if (t >= L_) return;
  float q[HD_];
  const float* qp = qkv + ((size_t)(b * L_ + t)) * 384 + h * HD_;
#pragma unroll
  for (int d4 = 0; d4 < HD_; d4 += 4) {
    float4 v = *(const float4*)(qp + d4);
    q[d4] = v.x; q[d4 + 1] = v.y; q[d4 + 2] = v.z; q[d4 + 3] = v.w;
  }
  float o[HD_];
#pragma unroll
  for (int d = 0; d < HD_; d++) o[d] = 0.f;
  float mrun = -INFINITY, lrun = 0.f;
  const float scale = 0.17677669529663687f;   // 1/sqrt(32)
  for (int j = 0; j <= t; j++) {
    float s = 0.f;
#pragma unroll
    for (int d = 0; d < HD_; d++) s += q[d] * ks[j][d];
    s *= scale;
    float mn = fmaxf(mrun, s);
    float corr = __expf(mrun - mn);
    float p = __expf(s - mn);
    lrun = lrun * corr + p;
#pragma unroll
    for (int d = 0; d < HD_; d++) o[d] = o[d] * corr + p * vs[j][d];
    mrun = mn;
  }
  float inv = 1.f / lrun;
  float* op = Oq + ((size_t)(b * L_ + t)) * 384 + h * HD_;
#pragma unroll
  for (int d4 = 0; d4 < HD_; d4 += 4) {
    float4 v;
    v.x = o[d4] * inv; v.y = o[d4 + 1] * inv;
    v.z = o[d4 + 2] * inv; v.w = o[d4 + 3] * inv;
    *(float4*)(op + d4) = v;
  }
}

// ---------------------------------------------------------------- loss pieces
__global__ void k_zero(float* __restrict__ w_raw, float* __restrict__ reg_sq) {
  int t = threadIdx.x;
  if (t < 128) w_raw[t] = 0.f;
  if (t == 128) reg_sq[0] = 0.f;
}

__global__ __launch_bounds__(256) void k_wreg(const float* __restrict__ item_emb,
                                              const float* __restrict__ pred_w,
                                              float* __restrict__ w_raw,
                                              float* __restrict__ reg_sq) {
  int gw = (blockIdx.x * 256 + threadIdx.x) >> 6;
  int lane = threadIdx.x & 63;
  float2 p2 = *(const float2*)(pred_w + lane * 2);
  float ax = 0.f, ay = 0.f, ssq = 0.f;
  for (int r = gw; r < NITEMS; r += 1024) {
    float2 e = *(const float2*)(item_emb + (size_t)r * D_ + lane * 2);
    float dp = e.x * p2.x + e.y * p2.y;
#pragma unroll
    for (int o = 1; o < 64; o <<= 1) dp += __shfl_xor(dp, o, 64);
    ax += e.x * dp; ay += e.y * dp;
    ssq += e.x * e.x + e.y * e.y;
  }
  atomicAdd(&w_raw[lane * 2 + 0], ax);
  atomicAdd(&w_raw[lane * 2 + 1], ay);
#pragma unroll
  for (int o = 1; o < 64; o <<= 1) ssq += __shfl_xor(ssq, o, 64);
  if (lane == 0) atomicAdd(reg_sq, ssq);
}

__global__ void k_scale(const float* __restrict__ pred_w,
                        const float* __restrict__ w_raw,
                        const float* __restrict__ reg_sq,
                        float* __restrict__ wt, float* __restrict__ out) {
  int t = threadIdx.x;   // 128 threads
  __shared__ float sp[128];
  sp[t] = pred_w[t];
  __syncthreads();
  float S = 0.f;
  for (int i = 0; i < 128; i++) S += sp[i];
  wt[t] = C_ * S * w_raw[t];
  if (t == 0) out[0] = REG_ * sqrtf(reg_sq[0]);
}

__global__ __launch_bounds__(256) void k_final(const float* __restrict__ F,
                                               const int* __restrict__ pos_seqs,
                                               const float* __restrict__ item_emb,
                                               const float* __restrict__ pred_w,
                                               const float* __restrict__ wt,
                                               float* __restrict__ out) {
  int b = blockIdx.x;
  int wid = threadIdx.x >> 6, lane = threadIdx.x & 63;
  float2 wt2 = *(const float2*)(wt + lane * 2);
  float2 p2  = *(const float2*)(pred_w + lane * 2);
  float acc = 0.f;
  for (int s = wid; s < L_; s += 4) {
    float2 f = *(const float2*)(F + ((size_t)(b * L_ + s)) * D_ + lane * 2);
    int pi = pos_seqs[b * L_ + s];
    float2 pe = *(const float2*)(item_emb + (size_t)pi * D_ + lane * 2);
    float rsum = f.x + f.y;
    float dw = f.x * wt2.x + f.y * wt2.y;
    float rr = p2.x * f.x * pe.x + p2.y * f.y * pe.y;
#pragma unroll
    for (int o = 1; o < 64; o <<= 1) {
      rsum += __shfl_xor(rsum, o, 64);
      dw   += __shfl_xor(dw, o, 64);
      rr   += __shfl_xor(rr, o, 64);
    }
    acc += rsum * dw + (1.f - C_) * rr * rr - 2.f * rr;
  }
  if (lane == 0) atomicAdd(out, acc * (1.f / B_));
}

// ---------------------------------------------------------------- launch
extern "C" void kernel_launch(void* const* d_in, const int* in_sizes, int n_in,
                              void* d_out, int out_size, void* d_ws, size_t ws_size,
                              hipStream_t stream) {
  const int*   log_seqs = (const int*)d_in[1];
  const int*   pos_seqs = (const int*)d_in[2];
  const float* item_emb = (const float*)d_in[3];
  const float* pos_emb  = (const float*)d_in[4];
  const float* pred_w   = (const float*)d_in[5];
  const float* ln1_g = (const float*)d_in[6];
  const float* ln1_b = (const float*)d_in[7];
  const float* in_w  = (const float*)d_in[8];
  const float* in_b  = (const float*)d_in[9];
  const float* out_w = (const float*)d_in[10];
  const float* out_b = (const float*)d_in[11];
  const float* ln2_g = (const float*)d_in[12];
  const float* ln2_b = (const float*)d_in[13];
  const float* c1_w  = (const float*)d_in[14];
  const float* c1_b  = (const float*)d_in[15];
  const float* c2_w  = (const float*)d_in[16];
  const float* c2_b  = (const float*)d_in[17];
  float* out = (float*)d_out;

  char* ws = (char*)d_ws;
  const size_t UNIT = (size_t)NROWS * D_ * sizeof(float);   // 26.2 MB
  float* X     = (float*)ws; ws += UNIT;        // seqs / F
  float* QB    = (float*)ws; ws += UNIT;        // LN outputs / residual
  float* QKV   = (float*)ws; ws += 3 * UNIT;    // qkv (384-wide); also attn-out & FFN hidden
  float* w_raw = (float*)ws; ws += 512;
  float* wt    = (float*)ws; ws += 512;
  float* reg_sq= (float*)ws; ws += 512;
  if (ws_size < 5 * UNIT + 4096) return;

  k_zero<<<1, 256, 0, stream>>>(w_raw, reg_sq);
  k_embed<<<(NROWS * 32) / 256, 256, 0, stream>>>(log_seqs, item_emb, pos_emb, X);

  for (int i = 0; i < NB_; i++) {
    const float* iw = in_w + (size_t)i * 384 * 128;
    const float* ib = in_b + (size_t)i * 384;
    // Q = LN1(X)
    k_ln<<<NROWS / 4, 256, 0, stream>>>(X, ln1_g + i * 128, ln1_b + i * 128, QB);
    // q = QB @ Wq^T + bq          -> QKV[:, 0:128]
    k_gemm_mfma<<<dim3(NROWS / 64, 1), 256, 0, stream>>>(QB, 128, iw, ib, nullptr, QKV, 384, 0, 0);
    // k,v = X @ [Wk;Wv]^T + b     -> QKV[:, 128:384]  (2 chunks of 128)
    k_gemm_mfma<<<dim3(NROWS / 64, 2), 256, 0, stream>>>(X, 128, iw + 128 * 128, ib + 128,
                                                         nullptr, QKV, 384, 128, 0);
    // attention -> QKV[:, 0:128] (q slice, dead)
    k_attn<<<B_ * H_, 256, 0, stream>>>(QKV, QKV);
    // seqs = QB + attn @ Wo^T + bo -> X
    k_gemm_mfma<<<dim3(NROWS / 64, 1), 256, 0, stream>>>(QKV, 384, out_w + (size_t)i * 128 * 128,
                                                         out_b + i * 128, QB, X, 128, 0, 1);
    // Z = LN2 -> QB
    k_ln<<<NROWS / 4, 256, 0, stream>>>(X, ln2_g + i * 128, ln2_b + i * 128, QB);
    // H1 = relu(Z @ c1^T + b1) -> QKV (128-wide)
    k_gemm_mfma<<<dim3(NROWS / 64, 1), 256, 0, stream>>>(QB, 128, c1_w + (size_t)i * 128 * 128,
                                                         c1_b + i * 128, nullptr, QKV, 128, 0, 2);
    // X = Z + H1 @ c2^T + b2
    k_gemm_mfma<<<dim3(NROWS / 64, 1), 256, 0, stream>>>(QKV, 128, c2_w + (size_t)i * 128 * 128,
                                                         c2_b + i * 128, QB, X, 128, 0, 1);
  }

  k_wreg<<<256, 256, 0, stream>>>(item_emb, pred_w, w_raw, reg_sq);
  k_scale<<<1, 128, 0, stream>>>(pred_w, w_raw, reg_sq, wt, out);
  k_final<<<B_, 256, 0, stream>>>(X, pos_seqs, item_emb, pred_w, wt, out);
}

// Round 11
// 786.860 us; speedup vs baseline: 1.1303x; 1.0549x over previous
//
#include <hip/hip_runtime.h>
#include <math.h>

// SASRec loss on MI355X — round 10 bisection (resubmit; GPU unavailable):
// round-4 NaN'd; revert attention to round-3's validated f32 k_attn, KEEP
// pre-split-weight MFMA GEMM (k_convw + k_gemm2). Isolates NaN; banks GEMM win.
// B=256 L=200 D=128 H=4 NB=2, ITEMS=50000.
#define B_ 256
#define L_ 200
#define D_ 128
#define H_ 4
#define HD_ 32
#define NB_ 2
#define NROWS (B_ * L_)        // 51200
#define NITEMS 50001
#define EPS_ 1e-8f
#define C_ 0.001f
#define REG_ 0.0001f

typedef __bf16 bf16x8 __attribute__((ext_vector_type(8)));
typedef short  short8 __attribute__((ext_vector_type(8)));
typedef float  f32x4  __attribute__((ext_vector_type(4)));
typedef unsigned short us4 __attribute__((ext_vector_type(4)));

static __device__ __forceinline__ void split2(float f, unsigned short& h, unsigned short& l) {
  unsigned u = __builtin_bit_cast(unsigned, f);
  unsigned hb = (u + 0x7FFFu + ((u >> 16) & 1u)) >> 16;          // RTN-even hi
  float fl = f - __builtin_bit_cast(float, hb << 16);
  h = (unsigned short)hb;
  l = (unsigned short)(__builtin_bit_cast(unsigned, fl) >> 16);  // truncated lo
}

static __device__ __forceinline__ bf16x8 pack8(const unsigned short* s) {
  short8 v;
#pragma unroll
  for (int j = 0; j < 8; ++j) v[j] = (short)s[j];
  return __builtin_bit_cast(bf16x8, v);
}

// ---------------------------------------------------------------- weight split
// concatenated flat layout: in_w[0..98303] | out_w[98304..] | c1_w[131072..] | c2_w[163840..]
__global__ __launch_bounds__(256) void k_convw(const float* __restrict__ in_w,
                                               const float* __restrict__ out_w,
                                               const float* __restrict__ c1_w,
                                               const float* __restrict__ c2_w,
                                               unsigned short* __restrict__ Wh,
                                               unsigned short* __restrict__ Wl) {
  int i = (blockIdx.x * 256 + threadIdx.x) * 4;
  if (i >= 196608) return;
  const float* s; int j;
  if (i < 98304)       { s = in_w;  j = i; }
  else if (i < 131072) { s = out_w; j = i - 98304; }
  else if (i < 163840) { s = c1_w;  j = i - 131072; }
  else                 { s = c2_w;  j = i - 163840; }
  float4 v = *(const float4*)(s + j);
  float vf[4] = {v.x, v.y, v.z, v.w};
  us4 hv, lv;
#pragma unroll
  for (int t = 0; t < 4; ++t) {
    unsigned short h, l; split2(vf[t], h, l);
    hv[t] = h; lv[t] = l;
  }
  *(us4*)(Wh + i) = hv;
  *(us4*)(Wl + i) = lv;
}

// ---------------------------------------------------------------- embed
__global__ __launch_bounds__(256) void k_embed(const int* __restrict__ logs,
                                               const float* __restrict__ item_emb,
                                               const float* __restrict__ pos_emb,
                                               float* __restrict__ X) {
  int gid = blockIdx.x * 256 + threadIdx.x;
  if (gid >= NROWS * 32) return;
  int row = gid >> 5;
  int c4  = (gid & 31) << 2;
  int it  = logs[row];
  int l   = row % L_;
  int pos = (it != 0) ? (l + 1) : 0;
  float4 e = *(const float4*)(item_emb + (size_t)it * D_ + c4);
  float4 p = *(const float4*)(pos_emb + (size_t)pos * D_ + c4);
  float4 o; o.x = e.x + p.x; o.y = e.y + p.y; o.z = e.z + p.z; o.w = e.w + p.w;
  *(float4*)(X + (size_t)row * D_ + c4) = o;
}

// ---------------------------------------------------------------- layernorm
__global__ __launch_bounds__(256) void k_ln(const float* __restrict__ in,
                                            const float* __restrict__ g,
                                            const float* __restrict__ bb,
                                            float* __restrict__ out) {
  int wid = threadIdx.x >> 6, lane = threadIdx.x & 63;
  int row = blockIdx.x * 4 + wid;
  float2 x = *(const float2*)(in + (size_t)row * D_ + lane * 2);
  float s = x.x + x.y;
#pragma unroll
  for (int o = 1; o < 64; o <<= 1) s += __shfl_xor(s, o, 64);
  float m = s * (1.f / D_);
  float d0 = x.x - m, d1 = x.y - m;
  float ss = d0 * d0 + d1 * d1;
#pragma unroll
  for (int o = 1; o < 64; o <<= 1) ss += __shfl_xor(ss, o, 64);
  float rs = 1.f / sqrtf(ss * (1.f / D_) + EPS_);
  float2 gv = *(const float2*)(g + lane * 2);
  float2 bv = *(const float2*)(bb + lane * 2);
  float2 o2; o2.x = d0 * rs * gv.x + bv.x; o2.y = d1 * rs * gv.y + bv.y;
  *(float2*)(out + (size_t)row * D_ + lane * 2) = o2;
}

// ---------------------------------------------------------------- MFMA GEMM
// C[M,128-chunk] = epi(A[M,K=128] @ W[N,128]^T + bias, Res); W pre-split bf16.
// grid (M/64, chunks). 4 waves, each 64x32 output. epi: 0 bias, 1 +res, 2 relu.
__global__ __launch_bounds__(256) void k_gemm2(const float* __restrict__ A, int lda,
                                               const unsigned short* __restrict__ Wh,
                                               const unsigned short* __restrict__ Wl,
                                               const float* __restrict__ bias,
                                               const float* __restrict__ Res,
                                               float* __restrict__ Cmat, int ldc,
                                               int col0, int epi) {
  Wh   += (size_t)blockIdx.y * 128 * 128;
  Wl   += (size_t)blockIdx.y * 128 * 128;
  bias += blockIdx.y * 128;
  col0 += blockIdx.y * 128;
  __shared__ unsigned short Ah[64][136], Al[64][136];   // stride 272B (17x16B)
  const int tid  = threadIdx.x;
  const int bm   = blockIdx.x * 64;
  const int lane = tid & 63, wid = tid >> 6;
  const int n0   = wid * 32;
  const int fr   = lane & 15;
  const int fg   = lane >> 4;

  // W fragments (pre-split, direct 16B loads)
  bf16x8 wh[2][4], wl[2][4];
#pragma unroll
  for (int f = 0; f < 2; f++)
#pragma unroll
    for (int ks = 0; ks < 4; ks++) {
      const unsigned short* p = Wh + (size_t)(n0 + f * 16 + fr) * 128 + ks * 32 + fg * 8;
      const unsigned short* q = Wl + (size_t)(n0 + f * 16 + fr) * 128 + ks * 32 + fg * 8;
      wh[f][ks] = __builtin_bit_cast(bf16x8, *(const short8*)p);
      wl[f][ks] = __builtin_bit_cast(bf16x8, *(const short8*)q);
    }

  // stage A 64x128, split once per element
#pragma unroll
  for (int it = 0; it < 4; ++it) {
    int flat = it * 2048 + tid * 8;
    int r = flat >> 7, c = flat & 127;
    const float* ap = A + (size_t)(bm + r) * lda + c;
    float4 a0 = *(const float4*)ap;
    float4 a1 = *(const float4*)(ap + 4);
    float af[8] = {a0.x, a0.y, a0.z, a0.w, a1.x, a1.y, a1.z, a1.w};
    unsigned short hh[8], ll[8];
#pragma unroll
    for (int j = 0; j < 8; ++j) split2(af[j], hh[j], ll[j]);
    *(short8*)&Ah[r][c] = __builtin_bit_cast(short8, pack8(hh));
    *(short8*)&Al[r][c] = __builtin_bit_cast(short8, pack8(ll));
  }
  __syncthreads();

  f32x4 acc[4][2];
#pragma unroll
  for (int m = 0; m < 4; m++)
#pragma unroll
    for (int f = 0; f < 2; f++) acc[m][f] = (f32x4){0.f, 0.f, 0.f, 0.f};

#pragma unroll
  for (int m = 0; m < 4; m++) {
#pragma unroll
    for (int ks = 0; ks < 4; ks++) {
      bf16x8 ah = *(const bf16x8*)&Ah[m * 16 + fr][ks * 32 + fg * 8];
      bf16x8 al = *(const bf16x8*)&Al[m * 16 + fr][ks * 32 + fg * 8];
#pragma unroll
      for (int f = 0; f < 2; f++) {
        acc[m][f] = __builtin_amdgcn_mfma_f32_16x16x32_bf16(ah, wl[f][ks], acc[m][f], 0, 0, 0);
        acc[m][f] = __builtin_amdgcn_mfma_f32_16x16x32_bf16(al, wh[f][ks], acc[m][f], 0, 0, 0);
        acc[m][f] = __builtin_amdgcn_mfma_f32_16x16x32_bf16(ah, wh[f][ks], acc[m][f], 0, 0, 0);
      }
    }
  }

  // epilogue: C/D row=(lane>>4)*4+i, col=lane&15
#pragma unroll
  for (int f = 0; f < 2; f++) {
    int n = n0 + f * 16 + fr;
    float bv = bias[n];
#pragma unroll
    for (int m = 0; m < 4; m++) {
#pragma unroll
      for (int i = 0; i < 4; i++) {
        int row = bm + m * 16 + fg * 4 + i;
        float v = acc[m][f][i] + bv;
        if (epi == 2)      v = fmaxf(v, 0.f);
        else if (epi == 1) v += Res[(size_t)row * D_ + n];
        Cmat[(size_t)row * ldc + col0 + n] = v;
      }
    }
  }
}

// ---------------------------------------------------------------- attention
// round-3 validated version: one block per (b,h); K/V staged in LDS as f32;
// one thread per query row, online softmax. Output into the dead q slice.
__global__ __launch_bounds__(256) void k_attn(const float* __restrict__ qkv,
                                              float* __restrict__ Oq) {
  __shared__ float ks[L_][HD_];
  __shared__ float vs[L_][HD_];
  int b = blockIdx.x >> 2;    // H_ == 4
  int h = blockIdx.x & 3;
  int tid = threadIdx.x;
  for (int idx = tid; idx < L_ * HD_; idx += 256) {
    int j = idx >> 5, d = idx & 31;
    size_t base = ((size_t)(b * L_ + j)) * 384 + 128 + h * HD_ + d;
    ks[j][d] = qkv[base];
    vs[j][d] = qkv[base + 128];
  }
  __syncthreads();
  int t = tid;
  if (t >= L_) return;
  float q[HD_];
  const float* qp = qkv + ((size_t)(b * L_ + t)) * 384 + h * HD_;
#pragma unroll
  for (int d4 = 0; d4 < HD_; d4 += 4) {
    float4 v = *(const float4*)(qp + d4);
    q[d4] = v.x; q[d4 + 1] = v.y; q[d4 + 2] = v.z; q[d4 + 3] = v.w;
  }
  float o[HD_];
#pragma unroll
  for (int d = 0; d < HD_; d++) o[d] = 0.f;
  float mrun = -INFINITY, lrun = 0.f;
  const float scale = 0.17677669529663687f;   // 1/sqrt(32)
  for (int j = 0; j <= t; j++) {
    float s = 0.f;
#pragma unroll
    for (int d = 0; d < HD_; d++) s += q[d] * ks[j][d];
    s *= scale;
    float mn = fmaxf(mrun, s);
    float corr = __expf(mrun - mn);
    float p = __expf(s - mn);
    lrun = lrun * corr + p;
#pragma unroll
    for (int d = 0; d < HD_; d++) o[d] = o[d] * corr + p * vs[j][d];
    mrun = mn;
  }
  float inv = 1.f / lrun;
  float* op = Oq + ((size_t)(b * L_ + t)) * 384 + h * HD_;
#pragma unroll
  for (int d4 = 0; d4 < HD_; d4 += 4) {
    float4 v;
    v.x = o[d4] * inv; v.y = o[d4 + 1] * inv;
    v.z = o[d4 + 2] * inv; v.w = o[d4 + 3] * inv;
    *(float4*)(op + d4) = v;
  }
}

// ---------------------------------------------------------------- loss pieces
__global__ void k_zero(float* __restrict__ w_raw, float* __restrict__ reg_sq) {
  int t = threadIdx.x;
  if (t < 128) w_raw[t] = 0.f;
  if (t == 128) reg_sq[0] = 0.f;
}

__global__ __launch_bounds__(256) void k_wreg(const float* __restrict__ item_emb,
                                              const float* __restrict__ pred_w,
                                              float* __restrict__ w_raw,
                                              float* __restrict__ reg_sq) {
  int gw = (blockIdx.x * 256 + threadIdx.x) >> 6;
  int lane = threadIdx.x & 63;
  float2 p2 = *(const float2*)(pred_w + lane * 2);
  float ax = 0.f, ay = 0.f, ssq = 0.f;
  for (int r = gw; r < NITEMS; r += 1024) {
    float2 e = *(const float2*)(item_emb + (size_t)r * D_ + lane * 2);
    float dp = e.x * p2.x + e.y * p2.y;
#pragma unroll
    for (int o = 1; o < 64; o <<= 1) dp += __shfl_xor(dp, o, 64);
    ax += e.x * dp; ay += e.y * dp;
    ssq += e.x * e.x + e.y * e.y;
  }
  atomicAdd(&w_raw[lane * 2 + 0], ax);
  atomicAdd(&w_raw[lane * 2 + 1], ay);
#pragma unroll
  for (int o = 1; o < 64; o <<= 1) ssq += __shfl_xor(ssq, o, 64);
  if (lane == 0) atomicAdd(reg_sq, ssq);
}

__global__ void k_scale(const float* __restrict__ pred_w,
                        const float* __restrict__ w_raw,
                        const float* __restrict__ reg_sq,
                        float* __restrict__ wt, float* __restrict__ out) {
  int t = threadIdx.x;   // 128 threads
  __shared__ float sp[128];
  sp[t] = pred_w[t];
  __syncthreads();
  float S = 0.f;
  for (int i = 0; i < 128; i++) S += sp[i];
  wt[t] = C_ * S * w_raw[t];
  if (t == 0) out[0] = REG_ * sqrtf(reg_sq[0]);
}

__global__ __launch_bounds__(256) void k_final(const float* __restrict__ F,
                                               const int* __restrict__ pos_seqs,
                                               const float* __restrict__ item_emb,
                                               const float* __restrict__ pred_w,
                                               const float* __restrict__ wt,
                                               float* __restrict__ out) {
  int b = blockIdx.x;
  int wid = threadIdx.x >> 6, lane = threadIdx.x & 63;
  float2 wt2 = *(const float2*)(wt + lane * 2);
  float2 p2  = *(const float2*)(pred_w + lane * 2);
  float acc = 0.f;
  for (int s = wid; s < L_; s += 4) {
    float2 f = *(const float2*)(F + ((size_t)(b * L_ + s)) * D_ + lane * 2);
    int pi = pos_seqs[b * L_ + s];
    float2 pe = *(const float2*)(item_emb + (size_t)pi * D_ + lane * 2);
    float rsum = f.x + f.y;
    float dw = f.x * wt2.x + f.y * wt2.y;
    float rr = p2.x * f.x * pe.x + p2.y * f.y * pe.y;
#pragma unroll
    for (int o = 1; o < 64; o <<= 1) {
      rsum += __shfl_xor(rsum, o, 64);
      dw   += __shfl_xor(dw, o, 64);
      rr   += __shfl_xor(rr, o, 64);
    }
    acc += rsum * dw + (1.f - C_) * rr * rr - 2.f * rr;
  }
  if (lane == 0) atomicAdd(out, acc * (1.f / B_));
}

// ---------------------------------------------------------------- launch
extern "C" void kernel_launch(void* const* d_in, const int* in_sizes, int n_in,
                              void* d_out, int out_size, void* d_ws, size_t ws_size,
                              hipStream_t stream) {
  const int*   log_seqs = (const int*)d_in[1];
  const int*   pos_seqs = (const int*)d_in[2];
  const float* item_emb = (const float*)d_in[3];
  const float* pos_emb  = (const float*)d_in[4];
  const float* pred_w   = (const float*)d_in[5];
  const float* ln1_g = (const float*)d_in[6];
  const float* ln1_b = (const float*)d_in[7];
  const float* in_w  = (const float*)d_in[8];
  const float* in_b  = (const float*)d_in[9];
  const float* out_w = (const float*)d_in[10];
  const float* out_b = (const float*)d_in[11];
  const float* ln2_g = (const float*)d_in[12];
  const float* ln2_b = (const float*)d_in[13];
  const float* c1_w  = (const float*)d_in[14];
  const float* c1_b  = (const float*)d_in[15];
  const float* c2_w  = (const float*)d_in[16];
  const float* c2_b  = (const float*)d_in[17];
  float* out = (float*)d_out;

  char* ws = (char*)d_ws;
  const size_t UNIT = (size_t)NROWS * D_ * sizeof(float);   // 26.2 MB
  float* X     = (float*)ws; ws += UNIT;        // seqs / F
  float* QB    = (float*)ws; ws += UNIT;        // LN outputs / residual
  float* QKV   = (float*)ws; ws += 3 * UNIT;    // qkv 384-wide; attn-out & FFN hidden
  unsigned short* WH = (unsigned short*)ws; ws += 196608 * 2;
  unsigned short* WL = (unsigned short*)ws; ws += 196608 * 2;
  float* w_raw = (float*)ws; ws += 512;
  float* wt    = (float*)ws; ws += 512;
  float* reg_sq= (float*)ws; ws += 512;
  if (ws_size < 5 * UNIT + 4 * 196608 + 4096) return;

  // weight split offsets (elements)
  const size_t OFF_OUT = 98304, OFF_C1 = 131072, OFF_C2 = 163840;

  k_zero<<<1, 256, 0, stream>>>(w_raw, reg_sq);
  k_convw<<<192, 256, 0, stream>>>(in_w, out_w, c1_w, c2_w, WH, WL);
  k_embed<<<(NROWS * 32) / 256, 256, 0, stream>>>(log_seqs, item_emb, pos_emb, X);

  for (int i = 0; i < NB_; i++) {
    const size_t iwo = (size_t)i * 384 * 128;   // in_w block offset
    const size_t sqo = (size_t)i * 128 * 128;   // square weight offset
    const float* ib = in_b + (size_t)i * 384;
    // Q = LN1(X)
    k_ln<<<NROWS / 4, 256, 0, stream>>>(X, ln1_g + i * 128, ln1_b + i * 128, QB);
    // q = QB @ Wq^T + bq          -> QKV[:, 0:128]
    k_gemm2<<<dim3(NROWS / 64, 1), 256, 0, stream>>>(QB, 128, WH + iwo, WL + iwo,
                                                     ib, nullptr, QKV, 384, 0, 0);
    // k,v = X @ [Wk;Wv]^T + b     -> QKV[:, 128:384]
    k_gemm2<<<dim3(NROWS / 64, 2), 256, 0, stream>>>(X, 128, WH + iwo + 128 * 128,
                                                     WL + iwo + 128 * 128,
                                                     ib + 128, nullptr, QKV, 384, 128, 0);
    // attention -> QKV[:, 0:128] (q slice, dead)
    k_attn<<<B_ * H_, 256, 0, stream>>>(QKV, QKV);
    // seqs = QB + attn @ Wo^T + bo -> X
    k_gemm2<<<dim3(NROWS / 64, 1), 256, 0, stream>>>(QKV, 384, WH + OFF_OUT + sqo,
                                                     WL + OFF_OUT + sqo,
                                                     out_b + i * 128, QB, X, 128, 0, 1);
    // Z = LN2 -> QB
    k_ln<<<NROWS / 4, 256, 0, stream>>>(X, ln2_g + i * 128, ln2_b + i * 128, QB);
    // H1 = relu(Z @ c1^T + b1) -> QKV (128-wide)
    k_gemm2<<<dim3(NROWS / 64, 1), 256, 0, stream>>>(QB, 128, WH + OFF_C1 + sqo,
                                                     WL + OFF_C1 + sqo,
                                                     c1_b + i * 128, nullptr, QKV, 128, 0, 2);
    // X = Z + H1 @ c2^T + b2
    k_gemm2<<<dim3(NROWS / 64, 1), 256, 0, stream>>>(QKV, 128, WH + OFF_C2 + sqo,
                                                     WL + OFF_C2 + sqo,
                                                     c2_b + i * 128, QB, X, 128, 0, 1);
  }

  k_wreg<<<256, 256, 0, stream>>>(item_emb, pred_w, w_raw, reg_sq);
  k_scale<<<1, 128, 0, stream>>>(pred_w, w_raw, reg_sq, wt, out);
  k_final<<<B_, 256, 0, stream>>>(X, pos_seqs, item_emb, pred_w, wt, out);
}

// Round 12
// 688.153 us; speedup vs baseline: 1.2925x; 1.1434x over previous
//
#include <hip/hip_runtime.h>
#include <math.h>

// SASRec loss on MI355X — round 12: re-land MFMA flash attention with the
// NaN root-cause fix: V^T LDS arrays extended 208->224 (14 k-tiles) and
// zero-filled past L, so the qt=12 PV pair no longer reads uninitialized
// LDS (stale bf16-NaN patterns) as the B operand. GEMM path unchanged
// (validated round 11, absmax 0.0).
// B=256 L=200 D=128 H=4 NB=2, ITEMS=50000.
#define B_ 256
#define L_ 200
#define D_ 128
#define H_ 4
#define NB_ 2
#define NROWS (B_ * L_)        // 51200
#define NITEMS 50001
#define EPS_ 1e-8f
#define C_ 0.001f
#define REG_ 0.0001f
#define KPADK_ 208             // 13 k-tiles * 16 (K reads bounded by tile 12)
#define KPADV_ 224             // 14 k-tiles * 16 (PV phantom pair reads tile 13)

typedef __bf16 bf16x8 __attribute__((ext_vector_type(8)));
typedef short  short8 __attribute__((ext_vector_type(8)));
typedef float  f32x4  __attribute__((ext_vector_type(4)));
typedef unsigned short us4 __attribute__((ext_vector_type(4)));

static __device__ __forceinline__ void split2(float f, unsigned short& h, unsigned short& l) {
  unsigned u = __builtin_bit_cast(unsigned, f);
  unsigned hb = (u + 0x7FFFu + ((u >> 16) & 1u)) >> 16;          // RTN-even hi
  float fl = f - __builtin_bit_cast(float, hb << 16);
  h = (unsigned short)hb;
  l = (unsigned short)(__builtin_bit_cast(unsigned, fl) >> 16);  // truncated lo
}

static __device__ __forceinline__ bf16x8 pack8(const unsigned short* s) {
  short8 v;
#pragma unroll
  for (int j = 0; j < 8; ++j) v[j] = (short)s[j];
  return __builtin_bit_cast(bf16x8, v);
}

// ---------------------------------------------------------------- weight split
// concatenated flat layout: in_w[0..98303] | out_w[98304..] | c1_w[131072..] | c2_w[163840..]
__global__ __launch_bounds__(256) void k_convw(const float* __restrict__ in_w,
                                               const float* __restrict__ out_w,
                                               const float* __restrict__ c1_w,
                                               const float* __restrict__ c2_w,
                                               unsigned short* __restrict__ Wh,
                                               unsigned short* __restrict__ Wl) {
  int i = (blockIdx.x * 256 + threadIdx.x) * 4;
  if (i >= 196608) return;
  const float* s; int j;
  if (i < 98304)       { s = in_w;  j = i; }
  else if (i < 131072) { s = out_w; j = i - 98304; }
  else if (i < 163840) { s = c1_w;  j = i - 131072; }
  else                 { s = c2_w;  j = i - 163840; }
  float4 v = *(const float4*)(s + j);
  float vf[4] = {v.x, v.y, v.z, v.w};
  us4 hv, lv;
#pragma unroll
  for (int t = 0; t < 4; ++t) {
    unsigned short h, l; split2(vf[t], h, l);
    hv[t] = h; lv[t] = l;
  }
  *(us4*)(Wh + i) = hv;
  *(us4*)(Wl + i) = lv;
}

// ---------------------------------------------------------------- embed
__global__ __launch_bounds__(256) void k_embed(const int* __restrict__ logs,
                                               const float* __restrict__ item_emb,
                                               const float* __restrict__ pos_emb,
                                               float* __restrict__ X) {
  int gid = blockIdx.x * 256 + threadIdx.x;
  if (gid >= NROWS * 32) return;
  int row = gid >> 5;
  int c4  = (gid & 31) << 2;
  int it  = logs[row];
  int l   = row % L_;
  int pos = (it != 0) ? (l + 1) : 0;
  float4 e = *(const float4*)(item_emb + (size_t)it * D_ + c4);
  float4 p = *(const float4*)(pos_emb + (size_t)pos * D_ + c4);
  float4 o; o.x = e.x + p.x; o.y = e.y + p.y; o.z = e.z + p.z; o.w = e.w + p.w;
  *(float4*)(X + (size_t)row * D_ + c4) = o;
}

// ---------------------------------------------------------------- layernorm
__global__ __launch_bounds__(256) void k_ln(const float* __restrict__ in,
                                            const float* __restrict__ g,
                                            const float* __restrict__ bb,
                                            float* __restrict__ out) {
  int wid = threadIdx.x >> 6, lane = threadIdx.x & 63;
  int row = blockIdx.x * 4 + wid;
  float2 x = *(const float2*)(in + (size_t)row * D_ + lane * 2);
  float s = x.x + x.y;
#pragma unroll
  for (int o = 1; o < 64; o <<= 1) s += __shfl_xor(s, o, 64);
  float m = s * (1.f / D_);
  float d0 = x.x - m, d1 = x.y - m;
  float ss = d0 * d0 + d1 * d1;
#pragma unroll
  for (int o = 1; o < 64; o <<= 1) ss += __shfl_xor(ss, o, 64);
  float rs = 1.f / sqrtf(ss * (1.f / D_) + EPS_);
  float2 gv = *(const float2*)(g + lane * 2);
  float2 bv = *(const float2*)(bb + lane * 2);
  float2 o2; o2.x = d0 * rs * gv.x + bv.x; o2.y = d1 * rs * gv.y + bv.y;
  *(float2*)(out + (size_t)row * D_ + lane * 2) = o2;
}

// ---------------------------------------------------------------- MFMA GEMM
// C[M,128-chunk] = epi(A[M,K=128] @ W[N,128]^T + bias, Res); W pre-split bf16.
// grid (M/64, chunks). 4 waves, each 64x32 output. epi: 0 bias, 1 +res, 2 relu.
__global__ __launch_bounds__(256) void k_gemm2(const float* __restrict__ A, int lda,
                                               const unsigned short* __restrict__ Wh,
                                               const unsigned short* __restrict__ Wl,
                                               const float* __restrict__ bias,
                                               const float* __restrict__ Res,
                                               float* __restrict__ Cmat, int ldc,
                                               int col0, int epi) {
  Wh   += (size_t)blockIdx.y * 128 * 128;
  Wl   += (size_t)blockIdx.y * 128 * 128;
  bias += blockIdx.y * 128;
  col0 += blockIdx.y * 128;
  __shared__ unsigned short Ah[64][136], Al[64][136];   // stride 272B (17x16B)
  const int tid  = threadIdx.x;
  const int bm   = blockIdx.x * 64;
  const int lane = tid & 63, wid = tid >> 6;
  const int n0   = wid * 32;
  const int fr   = lane & 15;
  const int fg   = lane >> 4;

  // W fragments (pre-split, direct 16B loads)
  bf16x8 wh[2][4], wl[2][4];
#pragma unroll
  for (int f = 0; f < 2; f++)
#pragma unroll
    for (int ks = 0; ks < 4; ks++) {
      const unsigned short* p = Wh + (size_t)(n0 + f * 16 + fr) * 128 + ks * 32 + fg * 8;
      const unsigned short* q = Wl + (size_t)(n0 + f * 16 + fr) * 128 + ks * 32 + fg * 8;
      wh[f][ks] = __builtin_bit_cast(bf16x8, *(const short8*)p);
      wl[f][ks] = __builtin_bit_cast(bf16x8, *(const short8*)q);
    }

  // stage A 64x128, split once per element
#pragma unroll
  for (int it = 0; it < 4; ++it) {
    int flat = it * 2048 + tid * 8;
    int r = flat >> 7, c = flat & 127;
    const float* ap = A + (size_t)(bm + r) * lda + c;
    float4 a0 = *(const float4*)ap;
    float4 a1 = *(const float4*)(ap + 4);
    float af[8] = {a0.x, a0.y, a0.z, a0.w, a1.x, a1.y, a1.z, a1.w};
    unsigned short hh[8], ll[8];
#pragma unroll
    for (int j = 0; j < 8; ++j) split2(af[j], hh[j], ll[j]);
    *(short8*)&Ah[r][c] = __builtin_bit_cast(short8, pack8(hh));
    *(short8*)&Al[r][c] = __builtin_bit_cast(short8, pack8(ll));
  }
  __syncthreads();

  f32x4 acc[4][2];
#pragma unroll
  for (int m = 0; m < 4; m++)
#pragma unroll
    for (int f = 0; f < 2; f++) acc[m][f] = (f32x4){0.f, 0.f, 0.f, 0.f};

#pragma unroll
  for (int m = 0; m < 4; m++) {
#pragma unroll
    for (int ks = 0; ks < 4; ks++) {
      bf16x8 ah = *(const bf16x8*)&Ah[m * 16 + fr][ks * 32 + fg * 8];
      bf16x8 al = *(const bf16x8*)&Al[m * 16 + fr][ks * 32 + fg * 8];
#pragma unroll
      for (int f = 0; f < 2; f++) {
        acc[m][f] = __builtin_amdgcn_mfma_f32_16x16x32_bf16(ah, wl[f][ks], acc[m][f], 0, 0, 0);
        acc[m][f] = __builtin_amdgcn_mfma_f32_16x16x32_bf16(al, wh[f][ks], acc[m][f], 0, 0, 0);
        acc[m][f] = __builtin_amdgcn_mfma_f32_16x16x32_bf16(ah, wh[f][ks], acc[m][f], 0, 0, 0);
      }
    }
  }

  // epilogue: C/D row=(lane>>4)*4+i, col=lane&15
#pragma unroll
  for (int f = 0; f < 2; f++) {
    int n = n0 + f * 16 + fr;
    float bv = bias[n];
#pragma unroll
    for (int m = 0; m < 4; m++) {
#pragma unroll
      for (int i = 0; i < 4; i++) {
        int row = bm + m * 16 + fg * 4 + i;
        float v = acc[m][f][i] + bv;
        if (epi == 2)      v = fmaxf(v, 0.f);
        else if (epi == 1) v += Res[(size_t)row * D_ + n];
        Cmat[(size_t)row * ldc + col0 + n] = v;
      }
    }
  }
}

// ---------------------------------------------------------------- attention
// One block per (b,h); 4 waves; wave w does q-tiles w, w+4, w+8, w+12.
// S^T tile = mfma(K_frag, Q_frag) (split bf16). Softmax over k (regs + 2 shfl).
// P exported to A-frag layout via lane shfl; O = P@V (split bf16, V^T in LDS).
// FIX vs round 9: V arrays are 224 wide (14 tiles) and zero-filled for k>=L,
// so pair-6 PV reads (k 208..223) hit zeros, not uninitialized LDS (NaN).
__global__ __launch_bounds__(256) void k_attn2(const float* __restrict__ qkv,
                                               float* __restrict__ Oq) {
  __shared__ unsigned short Kh[KPADK_][32], Kl[KPADK_][32];   // [k][d]
  __shared__ unsigned short Vh[32][KPADV_], Vl[32][KPADV_];   // [d][k] (transposed)
  const int b = blockIdx.x >> 2, h = blockIdx.x & 3;
  const int tid = threadIdx.x, lane = tid & 63, w = tid >> 6;
  const size_t rb = (size_t)b * L_;

  // ---- stage K (hi/lo), pair-packed writes (rows >= L clamp; masked later)
#pragma unroll
  for (int it = 0; it < 13; ++it) {
    int e = it * 256 + tid;             // 0..3327 (208*16 pairs)
    int r = e >> 4;                     // k row 0..207
    int d2 = (e & 15) * 2;
    int src = r < L_ ? r : L_ - 1;
    const float* kp = qkv + (rb + src) * 384 + 128 + h * 32 + d2;
    float2 kv2 = *(const float2*)kp;
    unsigned short h0, l0, h1, l1;
    split2(kv2.x, h0, l0); split2(kv2.y, h1, l1);
    *(unsigned*)&Kh[r][d2] = (unsigned)h0 | ((unsigned)h1 << 16);
    *(unsigned*)&Kl[r][d2] = (unsigned)l0 | ((unsigned)l1 << 16);
  }
  // ---- stage V transposed (hi/lo); ZERO for k >= L (phantom-tile safety)
#pragma unroll
  for (int it = 0; it < 14; ++it) {
    int e = it * 256 + tid;             // 0..3583 (32 d * 112 k-pairs)
    int d = e & 31, k = (e >> 5) * 2;   // k even 0..222
    float v0 = (k     < L_) ? qkv[(rb + k    ) * 384 + 256 + h * 32 + d] : 0.f;
    float v1 = (k + 1 < L_) ? qkv[(rb + k + 1) * 384 + 256 + h * 32 + d] : 0.f;
    unsigned short h0, l0, h1, l1;
    split2(v0, h0, l0); split2(v1, h1, l1);
    *(unsigned*)&Vh[d][k] = (unsigned)h0 | ((unsigned)h1 << 16);
    *(unsigned*)&Vl[d][k] = (unsigned)l0 | ((unsigned)l1 << 16);
  }
  __syncthreads();

  const float scale = 0.17677669529663687f;   // 1/sqrt(32)
  const int fr = lane & 15, g = lane >> 4;
  f32x4 ps[14];
#pragma unroll
  for (int t = 0; t < 14; ++t) ps[t] = (f32x4){0.f, 0.f, 0.f, 0.f};

  for (int qi = 0; qi < 4; ++qi) {
    int qt = w + qi * 4;
    if (qt >= 13) break;
    const int ntiles = qt + 1;
    const int q = qt * 16 + fr;               // this lane's q column
    // Q fragment (B-operand: col=fr, d=8g+j)
    int qsrc = q < L_ ? q : L_ - 1;
    const float* qp = qkv + (rb + qsrc) * 384 + h * 32 + g * 8;
    float4 q0 = *(const float4*)qp, q1 = *(const float4*)(qp + 4);
    float qf[8] = {q0.x, q0.y, q0.z, q0.w, q1.x, q1.y, q1.z, q1.w};
    unsigned short qh_[8], ql_[8];
#pragma unroll
    for (int j = 0; j < 8; ++j) split2(qf[j], qh_[j], ql_[j]);
    bf16x8 qh = pack8(qh_), ql = pack8(ql_);

    // ---- scores S^T (tile rows k, cols q)
#pragma unroll
    for (int kt = 0; kt < 13; ++kt) {
      if (kt > qt) break;
      bf16x8 kh = *(const bf16x8*)&Kh[kt * 16 + fr][g * 8];
      bf16x8 kl = *(const bf16x8*)&Kl[kt * 16 + fr][g * 8];
      f32x4 s = (f32x4){0.f, 0.f, 0.f, 0.f};
      s = __builtin_amdgcn_mfma_f32_16x16x32_bf16(kh, ql, s, 0, 0, 0);
      s = __builtin_amdgcn_mfma_f32_16x16x32_bf16(kl, qh, s, 0, 0, 0);
      s = __builtin_amdgcn_mfma_f32_16x16x32_bf16(kh, qh, s, 0, 0, 0);
#pragma unroll
      for (int i = 0; i < 4; ++i) {
        int k = kt * 16 + g * 4 + i;
        ps[kt][i] = (k <= q && k < L_) ? s[i] * scale : -1e30f;
      }
    }
    // ---- softmax over k (per q column = per fr, spread over lane groups)
    float m = -1e30f;
#pragma unroll
    for (int kt = 0; kt < 13; ++kt) {
      if (kt > qt) break;
      m = fmaxf(m, fmaxf(fmaxf(ps[kt][0], ps[kt][1]), fmaxf(ps[kt][2], ps[kt][3])));
    }
    m = fmaxf(m, __shfl_xor(m, 16, 64));
    m = fmaxf(m, __shfl_xor(m, 32, 64));
    float lsum = 0.f;
#pragma unroll
    for (int kt = 0; kt < 13; ++kt) {
      if (kt > qt) break;
#pragma unroll
      for (int i = 0; i < 4; ++i) {
        float p = __expf(ps[kt][i] - m);
        ps[kt][i] = p;
        lsum += p;
      }
    }
    lsum += __shfl_xor(lsum, 16, 64);
    lsum += __shfl_xor(lsum, 32, 64);
    float rcp = 1.f / lsum;
    float linv[4];
#pragma unroll
    for (int i = 0; i < 4; ++i) linv[i] = __shfl(rcp, 4 * g + i, 64);

    // ---- PV: O = P @ V  (A=P via shfl exchange, B=V^T from LDS)
    const int npairs = (ntiles + 1) >> 1;
    f32x4 o0 = (f32x4){0.f, 0.f, 0.f, 0.f};
    f32x4 o1 = (f32x4){0.f, 0.f, 0.f, 0.f};
#pragma unroll
    for (int p = 0; p < 7; ++p) {
      if (p >= npairs) break;
      unsigned short pha[8], pla[8];
#pragma unroll
      for (int j = 0; j < 8; ++j) {
        int src = fr + 32 * ((lane >> 4) & 1) + 16 * (j >> 2);
        float v0 = __shfl(ps[2 * p][j & 3], src, 64);
        float v1 = __shfl(ps[2 * p + 1][j & 3], src, 64);
        float v = (lane >= 32) ? v1 : v0;
        split2(v, pha[j], pla[j]);
      }
      bf16x8 pah = pack8(pha), pal = pack8(pla);
      bf16x8 vh0 = *(const bf16x8*)&Vh[fr][p * 32 + g * 8];
      bf16x8 vl0 = *(const bf16x8*)&Vl[fr][p * 32 + g * 8];
      bf16x8 vh1 = *(const bf16x8*)&Vh[16 + fr][p * 32 + g * 8];
      bf16x8 vl1 = *(const bf16x8*)&Vl[16 + fr][p * 32 + g * 8];
      o0 = __builtin_amdgcn_mfma_f32_16x16x32_bf16(pah, vl0, o0, 0, 0, 0);
      o0 = __builtin_amdgcn_mfma_f32_16x16x32_bf16(pal, vh0, o0, 0, 0, 0);
      o0 = __builtin_amdgcn_mfma_f32_16x16x32_bf16(pah, vh0, o0, 0, 0, 0);
      o1 = __builtin_amdgcn_mfma_f32_16x16x32_bf16(pah, vl1, o1, 0, 0, 0);
      o1 = __builtin_amdgcn_mfma_f32_16x16x32_bf16(pal, vh1, o1, 0, 0, 0);
      o1 = __builtin_amdgcn_mfma_f32_16x16x32_bf16(pah, vh1, o1, 0, 0, 0);
    }
    // ---- write O: lane holds q=qt*16+4g+i (row), d = dhalf*16 + fr (col)
#pragma unroll
    for (int i = 0; i < 4; ++i) {
      int qrow = qt * 16 + 4 * g + i;
      if (qrow < L_) {
        float* op = Oq + (rb + qrow) * 384 + h * 32;
        op[fr]      = o0[i] * linv[i];
        op[16 + fr] = o1[i] * linv[i];
      }
    }
  }
}

// ---------------------------------------------------------------- loss pieces
__global__ void k_zero(float* __restrict__ w_raw, float* __restrict__ reg_sq) {
  int t = threadIdx.x;
  if (t < 128) w_raw[t] = 0.f;
  if (t == 128) reg_sq[0] = 0.f;
}

__global__ __launch_bounds__(256) void k_wreg(const float* __restrict__ item_emb,
                                              const float* __restrict__ pred_w,
                                              float* __restrict__ w_raw,
                                              float* __restrict__ reg_sq) {
  int gw = (blockIdx.x * 256 + threadIdx.x) >> 6;
  int lane = threadIdx.x & 63;
  float2 p2 = *(const float2*)(pred_w + lane * 2);
  float ax = 0.f, ay = 0.f, ssq = 0.f;
  for (int r = gw; r < NITEMS; r += 1024) {
    float2 e = *(const float2*)(item_emb + (size_t)r * D_ + lane * 2);
    float dp = e.x * p2.x + e.y * p2.y;
#pragma unroll
    for (int o = 1; o < 64; o <<= 1) dp += __shfl_xor(dp, o, 64);
    ax += e.x * dp; ay += e.y * dp;
    ssq += e.x * e.x + e.y * e.y;
  }
  atomicAdd(&w_raw[lane * 2 + 0], ax);
  atomicAdd(&w_raw[lane * 2 + 1], ay);
#pragma unroll
  for (int o = 1; o < 64; o <<= 1) ssq += __shfl_xor(ssq, o, 64);
  if (lane == 0) atomicAdd(reg_sq, ssq);
}

__global__ void k_scale(const float* __restrict__ pred_w,
                        const float* __restrict__ w_raw,
                        const float* __restrict__ reg_sq,
                        float* __restrict__ wt, float* __restrict__ out) {
  int t = threadIdx.x;   // 128 threads
  __shared__ float sp[128];
  sp[t] = pred_w[t];
  __syncthreads();
  float S = 0.f;
  for (int i = 0; i < 128; i++) S += sp[i];
  wt[t] = C_ * S * w_raw[t];
  if (t == 0) out[0] = REG_ * sqrtf(reg_sq[0]);
}

__global__ __launch_bounds__(256) void k_final(const float* __restrict__ F,
                                               const int* __restrict__ pos_seqs,
                                               const float* __restrict__ item_emb,
                                               const float* __restrict__ pred_w,
                                               const float* __restrict__ wt,
                                               float* __restrict__ out) {
  int b = blockIdx.x;
  int wid = threadIdx.x >> 6, lane = threadIdx.x & 63;
  float2 wt2 = *(const float2*)(wt + lane * 2);
  float2 p2  = *(const float2*)(pred_w + lane * 2);
  float acc = 0.f;
  for (int s = wid; s < L_; s += 4) {
    float2 f = *(const float2*)(F + ((size_t)(b * L_ + s)) * D_ + lane * 2);
    int pi = pos_seqs[b * L_ + s];
    float2 pe = *(const float2*)(item_emb + (size_t)pi * D_ + lane * 2);
    float rsum = f.x + f.y;
    float dw = f.x * wt2.x + f.y * wt2.y;
    float rr = p2.x * f.x * pe.x + p2.y * f.y * pe.y;
#pragma unroll
    for (int o = 1; o < 64; o <<= 1) {
      rsum += __shfl_xor(rsum, o, 64);
      dw   += __shfl_xor(dw, o, 64);
      rr   += __shfl_xor(rr, o, 64);
    }
    acc += rsum * dw + (1.f - C_) * rr * rr - 2.f * rr;
  }
  if (lane == 0) atomicAdd(out, acc * (1.f / B_));
}

// ---------------------------------------------------------------- launch
extern "C" void kernel_launch(void* const* d_in, const int* in_sizes, int n_in,
                              void* d_out, int out_size, void* d_ws, size_t ws_size,
                              hipStream_t stream) {
  const int*   log_seqs = (const int*)d_in[1];
  const int*   pos_seqs = (const int*)d_in[2];
  const float* item_emb = (const float*)d_in[3];
  const float* pos_emb  = (const float*)d_in[4];
  const float* pred_w   = (const float*)d_in[5];
  const float* ln1_g = (const float*)d_in[6];
  const float* ln1_b = (const float*)d_in[7];
  const float* in_w  = (const float*)d_in[8];
  const float* in_b  = (const float*)d_in[9];
  const float* out_w = (const float*)d_in[10];
  const float* out_b = (const float*)d_in[11];
  const float* ln2_g = (const float*)d_in[12];
  const float* ln2_b = (const float*)d_in[13];
  const float* c1_w  = (const float*)d_in[14];
  const float* c1_b  = (const float*)d_in[15];
  const float* c2_w  = (const float*)d_in[16];
  const float* c2_b  = (const float*)d_in[17];
  float* out = (float*)d_out;

  char* ws = (char*)d_ws;
  const size_t UNIT = (size_t)NROWS * D_ * sizeof(float);   // 26.2 MB
  float* X     = (float*)ws; ws += UNIT;        // seqs / F
  float* QB    = (float*)ws; ws += UNIT;        // LN outputs / residual
  float* QKV   = (float*)ws; ws += 3 * UNIT;    // qkv 384-wide; attn-out & FFN hidden
  unsigned short* WH = (unsigned short*)ws; ws += 196608 * 2;
  unsigned short* WL = (unsigned short*)ws; ws += 196608 * 2;
  float* w_raw = (float*)ws; ws += 512;
  float* wt    = (float*)ws; ws += 512;
  float* reg_sq= (float*)ws; ws += 512;
  if (ws_size < 5 * UNIT + 4 * 196608 + 4096) return;

  // weight split offsets (elements)
  const size_t OFF_OUT = 98304, OFF_C1 = 131072, OFF_C2 = 163840;

  k_zero<<<1, 256, 0, stream>>>(w_raw, reg_sq);
  k_convw<<<192, 256, 0, stream>>>(in_w, out_w, c1_w, c2_w, WH, WL);
  k_embed<<<(NROWS * 32) / 256, 256, 0, stream>>>(log_seqs, item_emb, pos_emb, X);

  for (int i = 0; i < NB_; i++) {
    const size_t iwo = (size_t)i * 384 * 128;   // in_w block offset
    const size_t sqo = (size_t)i * 128 * 128;   // square weight offset
    const float* ib = in_b + (size_t)i * 384;
    // Q = LN1(X)
    k_ln<<<NROWS / 4, 256, 0, stream>>>(X, ln1_g + i * 128, ln1_b + i * 128, QB);
    // q = QB @ Wq^T + bq          -> QKV[:, 0:128]
    k_gemm2<<<dim3(NROWS / 64, 1), 256, 0, stream>>>(QB, 128, WH + iwo, WL + iwo,
                                                     ib, nullptr, QKV, 384, 0, 0);
    // k,v = X @ [Wk;Wv]^T + b     -> QKV[:, 128:384]
    k_gemm2<<<dim3(NROWS / 64, 2), 256, 0, stream>>>(X, 128, WH + iwo + 128 * 128,
                                                     WL + iwo + 128 * 128,
                                                     ib + 128, nullptr, QKV, 384, 128, 0);
    // attention -> QKV[:, 0:128] (q slice, dead)
    k_attn2<<<B_ * H_, 256, 0, stream>>>(QKV, QKV);
    // seqs = QB + attn @ Wo^T + bo -> X
    k_gemm2<<<dim3(NROWS / 64, 1), 256, 0, stream>>>(QKV, 384, WH + OFF_OUT + sqo,
                                                     WL + OFF_OUT + sqo,
                                                     out_b + i * 128, QB, X, 128, 0, 1);
    // Z = LN2 -> QB
    k_ln<<<NROWS / 4, 256, 0, stream>>>(X, ln2_g + i * 128, ln2_b + i * 128, QB);
    // H1 = relu(Z @ c1^T + b1) -> QKV (128-wide)
    k_gemm2<<<dim3(NROWS / 64, 1), 256, 0, stream>>>(QB, 128, WH + OFF_C1 + sqo,
                                                     WL + OFF_C1 + sqo,
                                                     c1_b + i * 128, nullptr, QKV, 128, 0, 2);
    // X = Z + H1 @ c2^T + b2
    k_gemm2<<<dim3(NROWS / 64, 1), 256, 0, stream>>>(QKV, 128, WH + OFF_C2 + sqo,
                                                     WL + OFF_C2 + sqo,
                                                     c2_b + i * 128, QB, X, 128, 0, 1);
  }

  k_wreg<<<256, 256, 0, stream>>>(item_emb, pred_w, w_raw, reg_sq);
  k_scale<<<1, 128, 0, stream>>>(pred_w, w_raw, reg_sq, wt, out);
  k_final<<<B_, 256, 0, stream>>>(X, pos_seqs, item_emb, pred_w, wt, out);
}